// Round 2
// baseline (1814.940 us; speedup 1.0000x reference)
//
#include <hip/hip_runtime.h>
#include <math.h>

// Problem constants (B=4, S=2048, DIN=4096, DOUT=16384)
#define M_DIM 8192   // B*S
#define N_DIM 16384  // DOUT
#define K_DIM 4096   // DIN
#define KTILES (K_DIM / 64)

typedef _Float16 half8 __attribute__((ext_vector_type(8)));
typedef _Float16 half4v __attribute__((ext_vector_type(4)));
typedef float f32x4 __attribute__((ext_vector_type(4)));
typedef int i32x4 __attribute__((ext_vector_type(4)));

// async global->LDS, 16B per lane; LDS dest = wave-uniform base + lane*16
#define GLOAD_LDS16(gp, lp)                                                     \
  __builtin_amdgcn_global_load_lds(                                             \
      (const __attribute__((address_space(1))) unsigned int*)(gp),              \
      (__attribute__((address_space(3))) unsigned int*)(lp), 16, 0, 0)

#define MFMA16(a, b, c) __builtin_amdgcn_mfma_f32_16x16x32_f16((a), (b), (c), 0, 0, 0)

__device__ __forceinline__ float gelu_tanh(float y) {
  float t = tanhf(0.7978845608028654f * (y + 0.044715f * y * y * y));
  return 0.5f * y * (1.0f + t);
}

// ---------- conversion pre-passes (non-temporal reads: inputs are read once;
// keep writes cached so Ah/Wh stay L3-resident for the GEMM) ----------
__global__ void cvt_f32_to_f16_k(const float* __restrict__ in,
                                 _Float16* __restrict__ out, int n8) {
  int i = blockIdx.x * blockDim.x + threadIdx.x;
  if (i >= n8) return;
  const f32x4* p = (const f32x4*)in + 2 * (size_t)i;
  f32x4 a = __builtin_nontemporal_load(p);
  f32x4 b = __builtin_nontemporal_load(p + 1);
  half8 h;
  h[0] = (_Float16)a[0]; h[1] = (_Float16)a[1];
  h[2] = (_Float16)a[2]; h[3] = (_Float16)a[3];
  h[4] = (_Float16)b[0]; h[5] = (_Float16)b[1];
  h[6] = (_Float16)b[2]; h[7] = (_Float16)b[3];
  ((half8*)out)[i] = h;
}

__global__ void cvt_i32_to_f16_k(const int* __restrict__ in,
                                 _Float16* __restrict__ out, int n8) {
  int i = blockIdx.x * blockDim.x + threadIdx.x;
  if (i >= n8) return;
  const i32x4* p = (const i32x4*)in + 2 * (size_t)i;
  i32x4 a = __builtin_nontemporal_load(p);
  i32x4 b = __builtin_nontemporal_load(p + 1);
  half8 h;
  h[0] = (_Float16)(float)a[0]; h[1] = (_Float16)(float)a[1];
  h[2] = (_Float16)(float)a[2]; h[3] = (_Float16)(float)a[3];
  h[4] = (_Float16)(float)b[0]; h[5] = (_Float16)(float)b[1];
  h[6] = (_Float16)(float)b[2]; h[7] = (_Float16)(float)b[3];
  ((half8*)out)[i] = h;
}

// ---------- 256x256x64 counted-vmcnt pipelined GEMM, fused dequant+bias+GELU --
// 8 waves (2M x 4N), 512 threads, per-wave output 128x64 (8x4 16x16 frags).
// LDS layout: per buffer, per matrix, TWO K-SLABS (K-cols 0-31 / 32-63), each
// a contiguous 16 KiB region = one independently-waitable stage unit (2 gloads).
// Per tile, 4 phases; stage issue order A-s0, B-s0, A-s1, B-s1 (one unit/phase).
//   entry wait: vmcnt(4)  -> this tile's s0 units done; s1 units STAY IN FLIGHT
//   mid wait:   vmcnt(4)  -> this tile's s1 units done; next tile's s0 in flight
// vmcnt never drains to 0 in the main loop (T4); in-flight gloads overlap MFMAs.
// Swizzle within 64-B slab rows: byte ^= ((row>>1)&3)<<4, applied on the global
// SOURCE address (gload dest must be linear) and identically on the ds_read.
__global__ __launch_bounds__(512, 2) void q8gemm_gelu_256(
    const _Float16* __restrict__ Ah, const _Float16* __restrict__ Wh,
    const float* __restrict__ w_scale, const float* __restrict__ bias,
    float* __restrict__ out) {
  __shared__ _Float16 sA[2][2][8192];  // [buf][slab][row*32+col] 2x2x16 KiB
  __shared__ _Float16 sB[2][2][8192];

  const int tid = threadIdx.x;
  const int lane = tid & 63;
  const int wave = tid >> 6;   // 0..7
  const int ln15 = lane & 15;
  const int quad = lane >> 4;  // 0..3
  const int waveM = wave >> 2; // 0..1
  const int waveN = wave & 3;  // 0..3

  // XCD-aware swizzle (2048 blocks, %8==0 -> bijective), group-of-8 M tiles.
  int bid = blockIdx.x;
  int swz = (bid & 7) * 256 + (bid >> 3);
  int group = swz >> 9;
  int within = swz & 511;
  int pid_m = (group << 3) + (within & 7);
  int pid_n = within >> 3;

  const int rowA0 = pid_m * 256;
  const int rowB0 = pid_n * 256;

  // ---- staging source (per lane): lane l covers slab row wave*16+(l>>2)
  // (+128 for the 2nd gload of the unit), LDS colbyte (l&3)*16; global source
  // colbyte pre-XORed so LDS holds global[row][cb ^ ((row>>1&3)<<4)].
  const int kx = (((lane & 3) ^ ((lane >> 3) & 3)) << 3);  // f16 elems
  const _Float16* pA = Ah + (size_t)(rowA0 + wave * 16 + (lane >> 2)) * K_DIM + kx;
  const _Float16* pB = Wh + (size_t)(rowB0 + wave * 16 + (lane >> 2)) * K_DIM + kx;
  const int ldst = wave * 512;  // f16 elems within slab (wave-uniform)

  // ---- ds_read bases (f16 elems within a slab), same swizzle on read side.
  const int rowA = waveM * 128 + ln15;
  const int rowB = waveN * 64 + ln15;
  const int kq = quad << 4;  // bytes within 64-B slab row
  const int aBase = rowA * 32 + ((kq ^ (((rowA >> 1) & 3) << 4)) >> 1);  // +m*512
  const int bBase = rowB * 32 + ((kq ^ (((rowB >> 1) & 3) << 4)) >> 1);  // +n*512

  f32x4 acc[8][4] = {};

  // prologue: stage tile 0 (A-s0, B-s0, A-s1, B-s1), then entry wait
#pragma unroll
  for (int s = 0; s < 2; s++) {
    const _Float16* gA = pA + s * 32;
    const _Float16* gB = pB + s * 32;
    GLOAD_LDS16(gA, &sA[0][s][ldst]);
    GLOAD_LDS16(gA + (size_t)128 * K_DIM, &sA[0][s][4096 + ldst]);
    GLOAD_LDS16(gB, &sB[0][s][ldst]);
    GLOAD_LDS16(gB + (size_t)128 * K_DIM, &sB[0][s][4096 + ldst]);
  }
  // reorder note: issue order above is A-s0,A-s0,B-s0,B-s0,A-s1,A-s1,B-s1,B-s1
  asm volatile("s_waitcnt vmcnt(4)\ns_barrier" ::: "memory");

#pragma unroll 2
  for (int t = 0; t < KTILES; ++t) {
    const int cur = t & 1;
    const int nxt = cur ^ 1;
    const _Float16* As0 = &sA[cur][0][0];
    const _Float16* As1 = &sA[cur][1][0];
    const _Float16* Bs0 = &sB[cur][0][0];
    const _Float16* Bs1 = &sB[cur][1][0];
    const bool pf = (t + 1 < KTILES);
    const int tn = (t + 1) * 64;

    half8 af[8], bf[4];

    // ---- P0: read af slab0 (8) + bf0-1 slab0 (2); stage A-s0(t+1) ----
#pragma unroll
    for (int m = 0; m < 8; m++) af[m] = *(const half8*)&As0[aBase + m * 512];
    bf[0] = *(const half8*)&Bs0[bBase];
    bf[1] = *(const half8*)&Bs0[bBase + 512];
    if (pf) {
      const _Float16* g = pA + tn;
      GLOAD_LDS16(g, &sA[nxt][0][ldst]);
      GLOAD_LDS16(g + (size_t)128 * K_DIM, &sA[nxt][0][4096 + ldst]);
    }
    __builtin_amdgcn_s_barrier();
    __builtin_amdgcn_s_setprio(1);
#pragma unroll
    for (int m = 0; m < 8; m++) {
      acc[m][0] = MFMA16(af[m], bf[0], acc[m][0]);
      acc[m][1] = MFMA16(af[m], bf[1], acc[m][1]);
    }
    __builtin_amdgcn_s_setprio(0);
    __builtin_amdgcn_s_barrier();

    // ---- P1: read bf2-3 slab0 (2); stage B-s0(t+1) ----
    bf[2] = *(const half8*)&Bs0[bBase + 1024];
    bf[3] = *(const half8*)&Bs0[bBase + 1536];
    if (pf) {
      const _Float16* g = pB + tn;
      GLOAD_LDS16(g, &sB[nxt][0][ldst]);
      GLOAD_LDS16(g + (size_t)128 * K_DIM, &sB[nxt][0][4096 + ldst]);
    }
    __builtin_amdgcn_s_barrier();
    __builtin_amdgcn_s_setprio(1);
#pragma unroll
    for (int m = 0; m < 8; m++) {
      acc[m][2] = MFMA16(af[m], bf[2], acc[m][2]);
      acc[m][3] = MFMA16(af[m], bf[3], acc[m][3]);
    }
    __builtin_amdgcn_s_setprio(0);

    // ---- MID: this tile's s1 units done; next tile's s0 stays in flight ----
    if (pf)
      asm volatile("s_waitcnt vmcnt(4)\ns_barrier" ::: "memory");
    else
      asm volatile("s_waitcnt vmcnt(0)\ns_barrier" ::: "memory");

    // ---- P2: read af slab1 (8) + bf0-1 slab1 (2); stage A-s1(t+1) ----
#pragma unroll
    for (int m = 0; m < 8; m++) af[m] = *(const half8*)&As1[aBase + m * 512];
    bf[0] = *(const half8*)&Bs1[bBase];
    bf[1] = *(const half8*)&Bs1[bBase + 512];
    if (pf) {
      const _Float16* g = pA + tn + 32;
      GLOAD_LDS16(g, &sA[nxt][1][ldst]);
      GLOAD_LDS16(g + (size_t)128 * K_DIM, &sA[nxt][1][4096 + ldst]);
    }
    __builtin_amdgcn_s_barrier();
    __builtin_amdgcn_s_setprio(1);
#pragma unroll
    for (int m = 0; m < 8; m++) {
      acc[m][0] = MFMA16(af[m], bf[0], acc[m][0]);
      acc[m][1] = MFMA16(af[m], bf[1], acc[m][1]);
    }
    __builtin_amdgcn_s_setprio(0);
    __builtin_amdgcn_s_barrier();

    // ---- P3: read bf2-3 slab1 (2); stage B-s1(t+1) ----
    bf[2] = *(const half8*)&Bs1[bBase + 1024];
    bf[3] = *(const half8*)&Bs1[bBase + 1536];
    if (pf) {
      const _Float16* g = pB + tn + 32;
      GLOAD_LDS16(g, &sB[nxt][1][ldst]);
      GLOAD_LDS16(g + (size_t)128 * K_DIM, &sB[nxt][1][4096 + ldst]);
    }
    __builtin_amdgcn_s_barrier();
    __builtin_amdgcn_s_setprio(1);
#pragma unroll
    for (int m = 0; m < 8; m++) {
      acc[m][2] = MFMA16(af[m], bf[2], acc[m][2]);
      acc[m][3] = MFMA16(af[m], bf[3], acc[m][3]);
    }
    __builtin_amdgcn_s_setprio(0);

    // ---- END: next tile's s0 units done at loop top; s1 stays in flight ----
    asm volatile("s_waitcnt vmcnt(4)\ns_barrier" ::: "memory");
  }

  // epilogue: dequant * scale + bias, tanh-GELU, non-temporal fp32 store
  // (streams 512 MiB past the L3 so A/W panels stay resident).
  // C/D layout: col = ln15, row = quad*4 + r
#pragma unroll
  for (int n = 0; n < 4; n++) {
    int col = rowB0 + waveN * 64 + n * 16 + ln15;
    float sc = w_scale[col];
    float bi = bias[col];
#pragma unroll
    for (int m = 0; m < 8; m++) {
      int r0 = rowA0 + waveM * 128 + m * 16 + quad * 4;
#pragma unroll
      for (int r = 0; r < 4; r++) {
        float y = acc[m][n][r] * sc + bi;
        __builtin_nontemporal_store(gelu_tanh(y),
                                    &out[(size_t)(r0 + r) * N_DIM + col]);
      }
    }
  }
}

// ---------- fallback (tiny workspace): 128x128 kernel, convert inline ----
__global__ void q8gemm_gelu_fb(const float* __restrict__ Af,
                               const int* __restrict__ Wi,
                               const float* __restrict__ w_scale,
                               const float* __restrict__ bias,
                               float* __restrict__ out) {
  __shared__ _Float16 sA[128 * 32];
  __shared__ _Float16 sB[128 * 32];

  const int tid = threadIdx.x;
  const int lane = tid & 63;
  const int ln15 = lane & 15;
  const int quad = lane >> 4;
  const int wave = tid >> 6;
  const int waveM = wave >> 1;
  const int waveN = wave & 1;

  int bid = blockIdx.x;
  int group_id = bid >> 10;
  int within = bid & 1023;
  int pid_m = group_id * 8 + (within & 7);
  int pid_n = within >> 3;

  const int rowA0 = pid_m * 128;
  const int rowB0 = pid_n * 128;

  f32x4 acc[4][4] = {};

  int aOff[4], bOff[4];
#pragma unroll
  for (int i = 0; i < 4; i++) {
    aOff[i] = (waveM * 64 + i * 16 + ln15) * 32 + quad * 8;
    bOff[i] = (waveN * 64 + i * 16 + ln15) * 32 + quad * 8;
  }

  for (int k0 = 0; k0 < K_DIM; k0 += 32) {
#pragma unroll
    for (int i = 0; i < 4; i++) {
      int c = tid + i * 256;
      int r = c >> 3;
      int col = (c & 7) << 2;
      f32x4 av = *(const f32x4*)(Af + (size_t)(rowA0 + r) * K_DIM + k0 + col);
      half4v ah;
      ah[0] = (_Float16)av[0]; ah[1] = (_Float16)av[1];
      ah[2] = (_Float16)av[2]; ah[3] = (_Float16)av[3];
      *(half4v*)&sA[r * 32 + col] = ah;
      i32x4 wv = *(const i32x4*)(Wi + (size_t)(rowB0 + r) * K_DIM + k0 + col);
      half4v wh;
      wh[0] = (_Float16)(float)wv[0]; wh[1] = (_Float16)(float)wv[1];
      wh[2] = (_Float16)(float)wv[2]; wh[3] = (_Float16)(float)wv[3];
      *(half4v*)&sB[r * 32 + col] = wh;
    }
    __syncthreads();

    half8 aF[4], bF[4];
#pragma unroll
    for (int i = 0; i < 4; i++) {
      aF[i] = *(const half8*)&sA[aOff[i]];
      bF[i] = *(const half8*)&sB[bOff[i]];
    }
#pragma unroll
    for (int mi = 0; mi < 4; mi++)
#pragma unroll
      for (int ni = 0; ni < 4; ni++)
        acc[mi][ni] = MFMA16(aF[mi], bF[ni], acc[mi][ni]);

    __syncthreads();
  }

#pragma unroll
  for (int ni = 0; ni < 4; ni++) {
    int n_g = rowB0 + waveN * 64 + ni * 16 + ln15;
    float sc = w_scale[n_g];
    float bi = bias[n_g];
#pragma unroll
    for (int mi = 0; mi < 4; mi++) {
      int r0 = rowA0 + waveM * 64 + mi * 16 + quad * 4;
#pragma unroll
      for (int r = 0; r < 4; r++) {
        float y = acc[mi][ni][r] * sc + bi;
        out[(size_t)(r0 + r) * N_DIM + n_g] = gelu_tanh(y);
      }
    }
  }
}

extern "C" void kernel_launch(void* const* d_in, const int* in_sizes, int n_in,
                              void* d_out, int out_size, void* d_ws,
                              size_t ws_size, hipStream_t stream) {
  const float* hs = (const float*)d_in[0];   // [M,K] fp32
  const int* w8 = (const int*)d_in[1];       // [N,K] int32 (int8-valued)
  const float* wsc = (const float*)d_in[2];  // [N]
  const float* bs = (const float*)d_in[3];   // [N]
  float* out = (float*)d_out;                // [M,N] fp32

  const size_t needA = (size_t)M_DIM * K_DIM * sizeof(_Float16);  // 64 MiB
  const size_t needW = (size_t)N_DIM * K_DIM * sizeof(_Float16);  // 128 MiB

  if (ws_size >= needA + needW) {
    _Float16* Ah = (_Float16*)d_ws;
    _Float16* Wh = (_Float16*)((char*)d_ws + needA);
    int n8a = M_DIM * K_DIM / 8;
    int n8w = N_DIM * K_DIM / 8;
    cvt_f32_to_f16_k<<<n8a / 256, 256, 0, stream>>>(hs, Ah, n8a);
    cvt_i32_to_f16_k<<<n8w / 256, 256, 0, stream>>>(w8, Wh, n8w);
    const int nblocks = (M_DIM / 256) * (N_DIM / 256);  // 2048
    q8gemm_gelu_256<<<nblocks, 512, 0, stream>>>(Ah, Wh, wsc, bs, out);
  } else {
    const int nblocks = (M_DIM / 128) * (N_DIM / 128);  // 8192
    q8gemm_gelu_fb<<<nblocks, 256, 0, stream>>>(hs, w8, wsc, bs, out);
  }
}

// Round 3
// 1570.145 us; speedup vs baseline: 1.1559x; 1.1559x over previous
//
#include <hip/hip_runtime.h>
#include <math.h>

// Problem constants (B=4, S=2048, DIN=4096, DOUT=16384)
#define M_DIM 8192   // B*S
#define N_DIM 16384  // DOUT
#define K_DIM 4096   // DIN
#define KTILES (K_DIM / 64)

typedef _Float16 half8 __attribute__((ext_vector_type(8)));
typedef _Float16 half4v __attribute__((ext_vector_type(4)));
typedef float f32x4 __attribute__((ext_vector_type(4)));
typedef int i32x4 __attribute__((ext_vector_type(4)));

// async global->LDS, 16B per lane; LDS dest = wave-uniform base + lane*16
#define GLOAD_LDS16(gp, lp)                                                     \
  __builtin_amdgcn_global_load_lds(                                             \
      (const __attribute__((address_space(1))) unsigned int*)(gp),              \
      (__attribute__((address_space(3))) unsigned int*)(lp), 16, 0, 0)

#define MFMA16(a, b, c) __builtin_amdgcn_mfma_f32_16x16x32_f16((a), (b), (c), 0, 0, 0)

__device__ __forceinline__ float gelu_tanh(float y) {
  float t = tanhf(0.7978845608028654f * (y + 0.044715f * y * y * y));
  return 0.5f * y * (1.0f + t);
}

// ---------- conversion pre-passes (non-temporal reads: inputs are read once;
// keep writes cached so Ah/Wh stay L3-resident for the GEMM) ----------
__global__ void cvt_f32_to_f16_k(const float* __restrict__ in,
                                 _Float16* __restrict__ out, int n8) {
  int i = blockIdx.x * blockDim.x + threadIdx.x;
  if (i >= n8) return;
  const f32x4* p = (const f32x4*)in + 2 * (size_t)i;
  f32x4 a = __builtin_nontemporal_load(p);
  f32x4 b = __builtin_nontemporal_load(p + 1);
  half8 h;
  h[0] = (_Float16)a[0]; h[1] = (_Float16)a[1];
  h[2] = (_Float16)a[2]; h[3] = (_Float16)a[3];
  h[4] = (_Float16)b[0]; h[5] = (_Float16)b[1];
  h[6] = (_Float16)b[2]; h[7] = (_Float16)b[3];
  ((half8*)out)[i] = h;
}

__global__ void cvt_i32_to_f16_k(const int* __restrict__ in,
                                 _Float16* __restrict__ out, int n8) {
  int i = blockIdx.x * blockDim.x + threadIdx.x;
  if (i >= n8) return;
  const i32x4* p = (const i32x4*)in + 2 * (size_t)i;
  i32x4 a = __builtin_nontemporal_load(p);
  i32x4 b = __builtin_nontemporal_load(p + 1);
  half8 h;
  h[0] = (_Float16)(float)a[0]; h[1] = (_Float16)(float)a[1];
  h[2] = (_Float16)(float)a[2]; h[3] = (_Float16)(float)a[3];
  h[4] = (_Float16)(float)b[0]; h[5] = (_Float16)(float)b[1];
  h[6] = (_Float16)(float)b[2]; h[7] = (_Float16)(float)b[3];
  ((half8*)out)[i] = h;
}

// ---------- 256x256x64 GEMM, fused dequant+bias+GELU ----------
// 8 waves (2M x 4N), 512 threads, per-wave output 128x64 (8x4 16x16 frags).
// LDS: 2 x (A 32KiB + B 32KiB) = 128 KiB, double-buffered over K-tiles.
// Stage of tile t+1 issued at TOP of iteration t; single __syncthreads per
// tile at the END (drains vmcnt for next tile's staging, issued ~1 tile ago).
// NO internal barriers: one large region of 24 ds_read_b128 + 64 MFMA per
// tile, compiler-scheduled with exact counted lgkmcnt waits -> LDS pipe
// streams UNDER the matrix pipe instead of alternating with it (the R1
// lockstep-phase structure measured MfmaUtil=40% == serialized-pipes model).
// XOR swizzle byte ^= ((row&7)<<4): applied on the GLOBAL source address
// (global_load_lds dest must be linear) and identically on the ds_read side.
__global__ __launch_bounds__(512, 2) void q8gemm_gelu_256(
    const _Float16* __restrict__ Ah, const _Float16* __restrict__ Wh,
    const float* __restrict__ w_scale, const float* __restrict__ bias,
    float* __restrict__ out) {
  __shared__ _Float16 sA[2][256 * 64];  // 2 x 32 KiB
  __shared__ _Float16 sB[2][256 * 64];  // 2 x 32 KiB

  const int tid = threadIdx.x;
  const int lane = tid & 63;
  const int wave = tid >> 6;   // 0..7
  const int ln15 = lane & 15;
  const int quad = lane >> 4;  // 0..3
  const int waveM = wave >> 2; // 0..1
  const int waveN = wave & 3;  // 0..3

  // XCD-aware swizzle (2048 blocks, %8==0 -> bijective), group-of-8 M tiles.
  int bid = blockIdx.x;
  int swz = (bid & 7) * 256 + (bid >> 3);
  int group = swz >> 9;           // 512 blocks per group (8 m x 64 n)
  int within = swz & 511;
  int pid_m = (group << 3) + (within & 7);  // 0..31
  int pid_n = within >> 3;                  // 0..63

  const int rowA0 = pid_m * 256;
  const int rowB0 = pid_n * 256;

  // ---- staging source (per lane). One gload_lds instr covers 1024B of LDS
  // (64 rows per instr across the wave: wave w rows w*8..w*8+7, +64 per i).
  // LDS linear byte p -> row=p>>7, kbyte=(p&127)^((row&7)<<4)  (inverse==fwd).
  const int srow = wave * 8 + (lane >> 3);                     // 0..63
  const int kswz = ((lane & 7) ^ ((lane >> 3) & 7)) << 3;      // f16 elems
  const _Float16* gA = Ah + (size_t)(rowA0 + srow) * K_DIM + kswz;
  const _Float16* gB = Wh + (size_t)(rowB0 + srow) * K_DIM + kswz;
  const int ldst = wave * 512;  // halves; + i*4096 per instr

  // ---- ds_read bases (f16 elems), same swizzle on the read side.
  const int swzb = (ln15 & 7) << 4;                 // byte xor term
  const int kq = quad << 4;                         // kbyte within 64B half
  const int aK0 = ((kq ^ swzb) >> 1);               // kstep 0
  const int aK1 = (((64 | kq) ^ swzb) >> 1);        // kstep 1 (bit6 toggles)
  const int aRowBase = (waveM * 128 + ln15) * 64;   // + m*1024
  const int bRowBase = (waveN * 64 + ln15) * 64;    // + n*1024

  f32x4 acc[8][4] = {};

  // prologue: stage tile 0 into buf 0, full drain once (cold start)
#pragma unroll
  for (int i = 0; i < 4; i++) {
    GLOAD_LDS16(gA + (size_t)i * 64 * K_DIM, &sA[0][i * 4096 + ldst]);
    GLOAD_LDS16(gB + (size_t)i * 64 * K_DIM, &sB[0][i * 4096 + ldst]);
  }
  __syncthreads();

#pragma unroll 2
  for (int t = 0; t < KTILES; ++t) {
    const int cur = t & 1;
    // issue next tile's 8 loads NOW; they land during this iteration's MFMAs
    if (t + 1 < KTILES) {
      const _Float16* ga = gA + (size_t)(t + 1) * 64;
      const _Float16* gb = gB + (size_t)(t + 1) * 64;
#pragma unroll
      for (int i = 0; i < 4; i++) {
        GLOAD_LDS16(ga + (size_t)i * 64 * K_DIM, &sA[cur ^ 1][i * 4096 + ldst]);
        GLOAD_LDS16(gb + (size_t)i * 64 * K_DIM, &sB[cur ^ 1][i * 4096 + ldst]);
      }
    }
    // pin staging issue before the read/MFMA region
    __builtin_amdgcn_sched_barrier(0);

    const _Float16* As = sA[cur];
    const _Float16* Bs = sB[cur];

    half8 afL[4][2], afH[4][2], bf[4][2];

    // ---- one barrier-free region: 24 ds_read_b128 + 64 MFMA, source-ordered
    // so later reads can issue while earlier MFMAs drain (compiler inserts
    // exact counted lgkmcnt waits; no s_barrier to lockstep the pipes).

    // reads for Q0: A m0-3 (8) + B n0-1 (4)
#pragma unroll
    for (int m = 0; m < 4; m++) {
      afL[m][0] = *(const half8*)&As[aRowBase + m * 1024 + aK0];
      afL[m][1] = *(const half8*)&As[aRowBase + m * 1024 + aK1];
    }
#pragma unroll
    for (int n = 0; n < 2; n++) {
      bf[n][0] = *(const half8*)&Bs[bRowBase + n * 1024 + aK0];
      bf[n][1] = *(const half8*)&Bs[bRowBase + n * 1024 + aK1];
    }
    // Q0: m0-3 x n0-1
#pragma unroll
    for (int m = 0; m < 4; m++)
#pragma unroll
      for (int n = 0; n < 2; n++) {
        acc[m][n] = MFMA16(afL[m][0], bf[n][0], acc[m][n]);
        acc[m][n] = MFMA16(afL[m][1], bf[n][1], acc[m][n]);
      }

    // reads for Q1: B n2-3 (4)
#pragma unroll
    for (int n = 2; n < 4; n++) {
      bf[n][0] = *(const half8*)&Bs[bRowBase + n * 1024 + aK0];
      bf[n][1] = *(const half8*)&Bs[bRowBase + n * 1024 + aK1];
    }
    // Q1: m0-3 x n2-3
#pragma unroll
    for (int m = 0; m < 4; m++)
#pragma unroll
      for (int n = 2; n < 4; n++) {
        acc[m][n] = MFMA16(afL[m][0], bf[n][0], acc[m][n]);
        acc[m][n] = MFMA16(afL[m][1], bf[n][1], acc[m][n]);
      }

    // reads for Q2/Q3: A m4-7 (8)
#pragma unroll
    for (int m = 0; m < 4; m++) {
      afH[m][0] = *(const half8*)&As[aRowBase + (m + 4) * 1024 + aK0];
      afH[m][1] = *(const half8*)&As[aRowBase + (m + 4) * 1024 + aK1];
    }
    // Q2: m4-7 x n2-3
#pragma unroll
    for (int m = 0; m < 4; m++)
#pragma unroll
      for (int n = 2; n < 4; n++) {
        acc[m + 4][n] = MFMA16(afH[m][0], bf[n][0], acc[m + 4][n]);
        acc[m + 4][n] = MFMA16(afH[m][1], bf[n][1], acc[m + 4][n]);
      }
    // Q3: m4-7 x n0-1
#pragma unroll
    for (int m = 0; m < 4; m++)
#pragma unroll
      for (int n = 0; n < 2; n++) {
        acc[m + 4][n] = MFMA16(afH[m][0], bf[n][0], acc[m + 4][n]);
        acc[m + 4][n] = MFMA16(afH[m][1], bf[n][1], acc[m + 4][n]);
      }

    // single per-tile sync: drains lgkm (all frag reads consumed) and vmcnt
    // (next tile's staging, issued a whole tile ago) before buffer swap.
    __syncthreads();
  }

  // epilogue: dequant * scale + bias, tanh-GELU, non-temporal fp32 store
  // (streams 512 MiB past the L3 so A/W panels stay resident).
  // C/D layout: col = ln15, row = quad*4 + r
#pragma unroll
  for (int n = 0; n < 4; n++) {
    int col = rowB0 + waveN * 64 + n * 16 + ln15;
    float sc = w_scale[col];
    float bi = bias[col];
#pragma unroll
    for (int m = 0; m < 8; m++) {
      int r0 = rowA0 + waveM * 128 + m * 16 + quad * 4;
#pragma unroll
      for (int r = 0; r < 4; r++) {
        float y = acc[m][n][r] * sc + bi;
        __builtin_nontemporal_store(gelu_tanh(y),
                                    &out[(size_t)(r0 + r) * N_DIM + col]);
      }
    }
  }
}

// ---------- fallback (tiny workspace): 128x128 kernel, convert inline ----
__global__ void q8gemm_gelu_fb(const float* __restrict__ Af,
                               const int* __restrict__ Wi,
                               const float* __restrict__ w_scale,
                               const float* __restrict__ bias,
                               float* __restrict__ out) {
  __shared__ _Float16 sA[128 * 32];
  __shared__ _Float16 sB[128 * 32];

  const int tid = threadIdx.x;
  const int lane = tid & 63;
  const int ln15 = lane & 15;
  const int quad = lane >> 4;
  const int wave = tid >> 6;
  const int waveM = wave >> 1;
  const int waveN = wave & 1;

  int bid = blockIdx.x;
  int group_id = bid >> 10;
  int within = bid & 1023;
  int pid_m = group_id * 8 + (within & 7);
  int pid_n = within >> 3;

  const int rowA0 = pid_m * 128;
  const int rowB0 = pid_n * 128;

  f32x4 acc[4][4] = {};

  int aOff[4], bOff[4];
#pragma unroll
  for (int i = 0; i < 4; i++) {
    aOff[i] = (waveM * 64 + i * 16 + ln15) * 32 + quad * 8;
    bOff[i] = (waveN * 64 + i * 16 + ln15) * 32 + quad * 8;
  }

  for (int k0 = 0; k0 < K_DIM; k0 += 32) {
#pragma unroll
    for (int i = 0; i < 4; i++) {
      int c = tid + i * 256;
      int r = c >> 3;
      int col = (c & 7) << 2;
      f32x4 av = *(const f32x4*)(Af + (size_t)(rowA0 + r) * K_DIM + k0 + col);
      half4v ah;
      ah[0] = (_Float16)av[0]; ah[1] = (_Float16)av[1];
      ah[2] = (_Float16)av[2]; ah[3] = (_Float16)av[3];
      *(half4v*)&sA[r * 32 + col] = ah;
      i32x4 wv = *(const i32x4*)(Wi + (size_t)(rowB0 + r) * K_DIM + k0 + col);
      half4v wh;
      wh[0] = (_Float16)(float)wv[0]; wh[1] = (_Float16)(float)wv[1];
      wh[2] = (_Float16)(float)wv[2]; wh[3] = (_Float16)(float)wv[3];
      *(half4v*)&sB[r * 32 + col] = wh;
    }
    __syncthreads();

    half8 aF[4], bF[4];
#pragma unroll
    for (int i = 0; i < 4; i++) {
      aF[i] = *(const half8*)&sA[aOff[i]];
      bF[i] = *(const half8*)&sB[bOff[i]];
    }
#pragma unroll
    for (int mi = 0; mi < 4; mi++)
#pragma unroll
      for (int ni = 0; ni < 4; ni++)
        acc[mi][ni] = MFMA16(aF[mi], bF[ni], acc[mi][ni]);

    __syncthreads();
  }

#pragma unroll
  for (int ni = 0; ni < 4; ni++) {
    int n_g = rowB0 + waveN * 64 + ni * 16 + ln15;
    float sc = w_scale[n_g];
    float bi = bias[n_g];
#pragma unroll
    for (int mi = 0; mi < 4; mi++) {
      int r0 = rowA0 + waveM * 64 + mi * 16 + quad * 4;
#pragma unroll
      for (int r = 0; r < 4; r++) {
        float y = acc[mi][ni][r] * sc + bi;
        out[(size_t)(r0 + r) * N_DIM + n_g] = gelu_tanh(y);
      }
    }
  }
}

extern "C" void kernel_launch(void* const* d_in, const int* in_sizes, int n_in,
                              void* d_out, int out_size, void* d_ws,
                              size_t ws_size, hipStream_t stream) {
  const float* hs = (const float*)d_in[0];   // [M,K] fp32
  const int* w8 = (const int*)d_in[1];       // [N,K] int32 (int8-valued)
  const float* wsc = (const float*)d_in[2];  // [N]
  const float* bs = (const float*)d_in[3];   // [N]
  float* out = (float*)d_out;                // [M,N] fp32

  const size_t needA = (size_t)M_DIM * K_DIM * sizeof(_Float16);  // 64 MiB
  const size_t needW = (size_t)N_DIM * K_DIM * sizeof(_Float16);  // 128 MiB

  if (ws_size >= needA + needW) {
    _Float16* Ah = (_Float16*)d_ws;
    _Float16* Wh = (_Float16*)((char*)d_ws + needA);
    int n8a = M_DIM * K_DIM / 8;
    int n8w = N_DIM * K_DIM / 8;
    cvt_f32_to_f16_k<<<n8a / 256, 256, 0, stream>>>(hs, Ah, n8a);
    cvt_i32_to_f16_k<<<n8w / 256, 256, 0, stream>>>(w8, Wh, n8w);
    const int nblocks = (M_DIM / 256) * (N_DIM / 256);  // 2048
    q8gemm_gelu_256<<<nblocks, 512, 0, stream>>>(Ah, Wh, wsc, bs, out);
  } else {
    const int nblocks = (M_DIM / 128) * (N_DIM / 128);  // 8192
    q8gemm_gelu_fb<<<nblocks, 256, 0, stream>>>(hs, w8, wsc, bs, out);
  }
}